// Round 14
// baseline (83.199 us; speedup 1.0000x reference)
//
#include <hip/hip_runtime.h>
#include <hip/hip_bf16.h>

// InvButterflyLayer via MFMA (bf16 in, fp32 accum). B=256, MID=16384, C=16.
// Live cone: level lvl needs t < 2^(8-lvl); lvl0 t<256 -> x[0:8224).
//
// R14: MEASUREMENT ROUND. Kernels byte-identical to R13; ibf_A launched 4x
// (idempotent). dur = 4*T_A + T_BC + gaps  vs  R13's T_A + T_BC + g = 40.7
// => T_A = (dur - 40.7)/3. Splits the 40 us between A and BC.

#define OUT_HALF 2097152

typedef __attribute__((ext_vector_type(4))) float f32x4;
typedef __attribute__((ext_vector_type(8))) short s16x8;

__device__ __forceinline__ uint fsw(uint a) {
    return a ^ ((((a >> 6) ^ (a >> 8)) & 3u) << 4);
}
__device__ __forceinline__ ushort bfr(float f) {
    __hip_bfloat16 h = __float2bfloat16(f);
    union { __hip_bfloat16 h; ushort u; } cv; cv.h = h; return cv.u;
}
__device__ __forceinline__ uint pk(float a, float b) {
    return (uint)bfr(a) | ((uint)bfr(b) << 16);
}

// Generic tree level (used by A): A[plane p][16-row tiles] x W[child] -> next A.
__device__ __forceinline__ void tree_level(
    char* smb, const int lane, const int wave,
    uint AOff, uint NOff, int lgR, int lgNP, int nTiles,
    uint WOff, int wnb, uint LBOff, int bnb)
{
    const int m  = lane & 15;
    const int kg = lane >> 4;
    const int lgTPP = lgR - 4;
    for (int at = wave; at < nTiles; at += 4) {
        const int p  = at >> lgTPP;
        const int tc = at & ((1 << lgTPP) - 1);
        const int np = p & ((1 << lgNP) - 1);
        const int ii = p >> lgNP;
        s16x8 af = *(const s16x8*)(smb + AOff + (p << (lgR + 6)) +
                                   fsw((uint)((tc * 16 + m) * 64 + kg * 16)));
#pragma unroll
        for (int sib = 0; sib < 2; sib++) {
            const int nl = 2 * np + sib;
            s16x8 bf = *(const s16x8*)(smb + WOff +
                         fsw((uint)((wnb + nl) * 1024 + m * 64 + kg * 16)));
            float bv = *(const float*)(smb + LBOff + ((bnb + nl) * 16 + m) * 4);
            f32x4 acc = {bv, bv, bv, bv};
            acc = __builtin_amdgcn_mfma_f32_16x16x32_bf16(af, bf, acc, 0, 0, 0);
            const int p2 = (ii << (lgNP + 1)) + nl;
            const uint wb = NOff + (p2 << (lgR + 5));
            const int r2 = tc * 8 + kg * 2;
            *(uint*)(smb + wb + fsw((uint)(r2 * 64 + m * 4))) =
                pk(fmaxf(acc.x, 0.f), fmaxf(acc.y, 0.f));
            *(uint*)(smb + wb + fsw((uint)((r2 + 1) * 64 + m * 4))) =
                pk(fmaxf(acc.z, 0.f), fmaxf(acc.w, 0.f));
        }
    }
}

// ===================== Kernel A (identical to R13) =====================
__global__ __launch_bounds__(256, 4)
void ibf_A(const float* __restrict__ in_data, const float* __restrict__ mid_dense,
           const float* __restrict__ in_filter, const float* __restrict__ in_bias,
           const float* __restrict__ filters, const float* __restrict__ biases,
           uint* __restrict__ S3)
{
    __shared__ __align__(16) char smb[29760];
    const int tid = threadIdx.x, lane = tid & 63, wave = tid >> 6;
    const int b = blockIdx.x;
    const int th = blockIdx.y >> 1;
    const int i  = blockIdx.y & 1;

    {
        const float4* inb = (const float4*)in_data + (size_t)b * 8192 + th * 2048;
        const float4* mdb = (const float4*)mid_dense + th * 2048;
        for (int mp = tid; mp < 2064; mp += 256) {
            float4 iv = inb[mp], mv = mdb[mp];
            float xa = i ? iv.y * mv.y : iv.x * mv.x;
            float xb = i ? iv.w * mv.w : iv.z * mv.z;
            *(uint*)(smb + fsw((uint)(mp * 4))) = pk(xa, xb);
        }
    }
    for (int t = tid; t < 3584; t += 256) {
        int nidx = t >> 8, r = t & 255, d = r & 15, c = r >> 4;
        int lvl = (nidx < 2) ? 1 : ((nidx < 6) ? 2 : 3);
        int n = nidx - ((1 << lvl) - 2);
        const float* src = filters + (size_t)(lvl - 1) * 131072 + n * 512 + c * 16 + d;
        *(uint*)(smb + 12416 + fsw((uint)(nidx * 1024 + d * 64 + c * 4))) = pk(src[0], src[256]);
    }
    for (int t = tid; t < 512; t += 256) {
        int c = t >> 5, w2 = t & 31;
        *(uint*)(smb + 26752 + fsw((uint)(c * 128 + w2 * 4))) =
            pk(in_filter[(2 * w2) * 16 + c], in_filter[(2 * w2 + 1) * 16 + c]);
    }
    if (tid < 240) {
        float v;
        if (tid < 224) {
            int nidx = tid >> 4;
            int lvl = (nidx < 2) ? 1 : ((nidx < 6) ? 2 : 3);
            int n = nidx - ((1 << lvl) - 2);
            v = biases[(size_t)(lvl - 1) * 4096 + n * 16 + (tid & 15)];
        } else v = in_bias[tid - 224];
        *(float*)(smb + 28800 + tid * 4) = v;
    }
    __syncthreads();

    {
        const int m = lane & 15, kg = lane >> 4;
        s16x8 b0 = *(const s16x8*)(smb + 26752 + fsw((uint)(m * 128 + kg * 16)));
        s16x8 b1 = *(const s16x8*)(smb + 26752 + fsw((uint)(m * 128 + 64 + kg * 16)));
        float bv = *(const float*)(smb + 28800 + (224 + m) * 4);
        for (int at = wave; at < 8; at += 4) {
            int tc = at;
            s16x8 a0 = *(const s16x8*)(smb + fsw((uint)((tc * 16 + m) * 64 + kg * 16)));
            s16x8 a1 = *(const s16x8*)(smb + fsw((uint)((tc * 16 + m) * 64 + 64 + kg * 16)));
            f32x4 acc = {bv, bv, bv, bv};
            acc = __builtin_amdgcn_mfma_f32_16x16x32_bf16(a0, b0, acc, 0, 0, 0);
            acc = __builtin_amdgcn_mfma_f32_16x16x32_bf16(a1, b1, acc, 0, 0, 0);
            int r2 = tc * 8 + kg * 2;
            *(uint*)(smb + 8320 + fsw((uint)(r2 * 64 + m * 4))) =
                pk(fmaxf(acc.x, 0.f), fmaxf(acc.y, 0.f));
            *(uint*)(smb + 8320 + fsw((uint)((r2 + 1) * 64 + m * 4))) =
                pk(fmaxf(acc.z, 0.f), fmaxf(acc.w, 0.f));
        }
    }
    __syncthreads();
    tree_level(smb, lane, wave, 8320, 0,    6, 0, 4, 12416, 0, 28800, 0);  // lvl1
    __syncthreads();
    tree_level(smb, lane, wave, 0,    8320, 5, 1, 4, 12416, 2, 28800, 2);  // lvl2
    __syncthreads();
    {
        const int m = lane & 15, kg = lane >> 4;
        for (int at = wave; at < 4; at += 4) {
            s16x8 af = *(const s16x8*)(smb + 8320 + (at << 10) + fsw((uint)(m * 64 + kg * 16)));
#pragma unroll
            for (int sib = 0; sib < 2; sib++) {
                int n3 = 2 * at + sib;
                s16x8 bf = *(const s16x8*)(smb + 12416 +
                             fsw((uint)((6 + n3) * 1024 + m * 64 + kg * 16)));
                float bv = *(const float*)(smb + 28800 + ((6 + n3) * 16 + m) * 4);
                f32x4 acc = {bv, bv, bv, bv};
                acc = __builtin_amdgcn_mfma_f32_16x16x32_bf16(af, bf, acc, 0, 0, 0);
                int bi = 2 * b + i;
                int t4 = th * 8 + kg * 2;
                uint idx = ((uint)(n3 * 512 + bi) * 16 + t4) * 16 + m;
                S3[idx]      = pk(fmaxf(acc.x, 0.f), fmaxf(acc.y, 0.f));
                S3[idx + 16] = pk(fmaxf(acc.z, 0.f), fmaxf(acc.w, 0.f));
            }
        }
    }
}

// ========== Kernel BC (identical to R13) ==========
__global__ __launch_bounds__(256, 2)
void ibf_BC(const float* __restrict__ filters, const float* __restrict__ biases,
            const float* __restrict__ fea_dense, const uint* __restrict__ S3,
            float* __restrict__ out)
{
    __shared__ __align__(16) char smb[33536];
    const int tid = threadIdx.x, lane = tid & 63, wave = tid >> 6;
    const int n3 = blockIdx.x, chunk = blockIdx.y;
    const int m = lane & 15, kg = lane >> 4;

    for (int o = tid * 16; o < 16384; o += 4096)
        *(float4*)(smb + 16384 + o) = make_float4(0.f, 0.f, 0.f, 0.f);

    const float* FB1 = filters + (size_t)3 * 131072 + ((size_t)(n3 << 1)) * 512;
    const float* FB2 = filters + (size_t)4 * 131072 + ((size_t)(n3 << 2)) * 512;
    const float* FB3 = filters + (size_t)5 * 131072 + ((size_t)(n3 << 3)) * 512;
    const float* FB4 = filters + (size_t)6 * 131072 + ((size_t)(n3 << 4)) * 512;
    const float* FB5 = filters + (size_t)7 * 131072 + ((size_t)(n3 << 5)) * 512;
    const float* BB1 = biases + (size_t)3 * 4096 + (n3 << 1) * 16;
    const float* BB2 = biases + (size_t)4 * 4096 + (n3 << 2) * 16;
    const float* BB3 = biases + (size_t)5 * 4096 + (n3 << 3) * 16;
    const float* BB4 = biases + (size_t)6 * 4096 + (n3 << 4) * 16;
    const float* BB5 = biases + (size_t)7 * 4096 + (n3 << 5) * 16;

#define LDFRAG(dst, fb, nl)                                                  \
    {                                                                        \
        const float* s_ = (fb) + (nl) * 512 + m;                             \
        _Pragma("unroll")                                                    \
        for (int c4 = 0; c4 < 4; c4++) {                                     \
            int c_ = kg * 4 + c4;                                            \
            (&(dst).x)[c4] = pk(s_[c_ * 16], s_[256 + c_ * 16]);             \
        }                                                                    \
    }

    uint4 f4[2], f5[4];
    float b4[2], b5[4];
    LDFRAG(f4[0], FB1, 0); LDFRAG(f4[1], FB1, 1);
    b4[0] = BB1[m]; b4[1] = BB1[16 + m];
#pragma unroll
    for (int s = 0; s < 4; s++) { LDFRAG(f5[s], FB2, s); b5[s] = BB2[s * 16 + m]; }
    {
        const char* src = (const char*)S3 + ((size_t)n3 * 512 + chunk * 8) * 1024;
        for (int ci = tid; ci < 512; ci += 256)
            *(float4*)(smb + fsw((uint)(ci * 16))) = *(const float4*)(src + ci * 16);
    }
    __syncthreads();

    uint4 f6[4];
    float b6[4];
    {
        const int n0 = (wave >> 1) * 2;
        LDFRAG(f6[0], FB3, n0);     b6[0] = BB3[(n0) * 16 + m];
        LDFRAG(f6[1], FB3, n0 + 1); b6[1] = BB3[(n0 + 1) * 16 + m];
        LDFRAG(f6[2], FB3, n0 + 4); b6[2] = BB3[(n0 + 4) * 16 + m];
        LDFRAG(f6[3], FB3, n0 + 5); b6[3] = BB3[(n0 + 5) * 16 + m];
    }
#pragma unroll
    for (int t2 = 0; t2 < 2; t2++) {
        const int tc = wave + t2 * 4;
        s16x8 af = *(const s16x8*)(smb + fsw((uint)((tc * 16 + m) * 64 + kg * 16)));
#pragma unroll
        for (int sib = 0; sib < 2; sib++) {
            f32x4 acc = {b4[sib], b4[sib], b4[sib], b4[sib]};
            acc = __builtin_amdgcn_mfma_f32_16x16x32_bf16(af, *(const s16x8*)&f4[sib], acc, 0, 0, 0);
            const uint wb = 8192u + (uint)sib * 4096u;
            const int r2 = tc * 8 + kg * 2;
            *(uint*)(smb + wb + fsw((uint)(r2 * 64 + m * 4))) = pk(fmaxf(acc.x, 0.f), fmaxf(acc.y, 0.f));
            *(uint*)(smb + wb + fsw((uint)((r2 + 1) * 64 + m * 4))) = pk(fmaxf(acc.z, 0.f), fmaxf(acc.w, 0.f));
        }
    }
    __syncthreads();

    uint4 f7[4];
    float b7[4];
    {
        LDFRAG(f7[0], FB4, 2 * wave);     b7[0] = BB4[(2 * wave) * 16 + m];
        LDFRAG(f7[1], FB4, 2 * wave + 1); b7[1] = BB4[(2 * wave + 1) * 16 + m];
        LDFRAG(f7[2], FB4, 2 * wave + 8); b7[2] = BB4[(2 * wave + 8) * 16 + m];
        LDFRAG(f7[3], FB4, 2 * wave + 9); b7[3] = BB4[(2 * wave + 9) * 16 + m];
    }
#pragma unroll
    for (int t2 = 0; t2 < 2; t2++) {
        const int at = wave + t2 * 4;
        const int p = at >> 2, tc = at & 3;
        s16x8 af = *(const s16x8*)(smb + 8192 + p * 4096 + fsw((uint)((tc * 16 + m) * 64 + kg * 16)));
#pragma unroll
        for (int sib = 0; sib < 2; sib++) {
            const int nl = 2 * p + sib;
            f32x4 acc = {b5[nl], b5[nl], b5[nl], b5[nl]};
            acc = __builtin_amdgcn_mfma_f32_16x16x32_bf16(af, *(const s16x8*)&f5[nl], acc, 0, 0, 0);
            const uint wb = (uint)nl * 2048u;
            const int r2 = tc * 8 + kg * 2;
            *(uint*)(smb + wb + fsw((uint)(r2 * 64 + m * 4))) = pk(fmaxf(acc.x, 0.f), fmaxf(acc.y, 0.f));
            *(uint*)(smb + wb + fsw((uint)((r2 + 1) * 64 + m * 4))) = pk(fmaxf(acc.z, 0.f), fmaxf(acc.w, 0.f));
        }
    }
    __syncthreads();

    uint4 f8[8];
    float b8[8];
#pragma unroll
    for (int t4 = 0; t4 < 4; t4++) {
        const int at = wave + 4 * t4;
        LDFRAG(f8[2 * t4],     FB5, 2 * at);     b8[2 * t4]     = BB5[(2 * at) * 16 + m];
        LDFRAG(f8[2 * t4 + 1], FB5, 2 * at + 1); b8[2 * t4 + 1] = BB5[(2 * at + 1) * 16 + m];
    }
#pragma unroll
    for (int t2 = 0; t2 < 2; t2++) {
        const int at = wave + t2 * 4;
        const int p = at >> 1, tc = at & 1;
        s16x8 af = *(const s16x8*)(smb + p * 2048 + fsw((uint)((tc * 16 + m) * 64 + kg * 16)));
#pragma unroll
        for (int sib = 0; sib < 2; sib++) {
            const int nl = 2 * p + sib;
            const int fi = t2 * 2 + sib;
            f32x4 acc = {b6[fi], b6[fi], b6[fi], b6[fi]};
            acc = __builtin_amdgcn_mfma_f32_16x16x32_bf16(af, *(const s16x8*)&f6[fi], acc, 0, 0, 0);
            const uint wb = 8192u + (uint)nl * 1024u;
            const int r2 = tc * 8 + kg * 2;
            *(uint*)(smb + wb + fsw((uint)(r2 * 64 + m * 4))) = pk(fmaxf(acc.x, 0.f), fmaxf(acc.y, 0.f));
            *(uint*)(smb + wb + fsw((uint)((r2 + 1) * 64 + m * 4))) = pk(fmaxf(acc.z, 0.f), fmaxf(acc.w, 0.f));
        }
    }
    __syncthreads();

#pragma unroll
    for (int t2 = 0; t2 < 2; t2++) {
        const int p = wave + t2 * 4;
        s16x8 af = *(const s16x8*)(smb + 8192 + p * 1024 + fsw((uint)(m * 64 + kg * 16)));
#pragma unroll
        for (int sib = 0; sib < 2; sib++) {
            const int nl = 2 * p + sib;
            const int fi = t2 * 2 + sib;
            f32x4 acc = {b7[fi], b7[fi], b7[fi], b7[fi]};
            acc = __builtin_amdgcn_mfma_f32_16x16x32_bf16(af, *(const s16x8*)&f7[fi], acc, 0, 0, 0);
            const uint wb = (uint)nl * 512u;
            const int r2 = kg * 2;
            *(uint*)(smb + wb + fsw((uint)(r2 * 64 + m * 4))) = pk(fmaxf(acc.x, 0.f), fmaxf(acc.y, 0.f));
            *(uint*)(smb + wb + fsw((uint)((r2 + 1) * 64 + m * 4))) = pk(fmaxf(acc.z, 0.f), fmaxf(acc.w, 0.f));
        }
    }
    __syncthreads();

#pragma unroll
    for (int t4 = 0; t4 < 4; t4++) {
        const int at = wave + 4 * t4;
        s16x8 af = *(const s16x8*)(smb + at * 512 + fsw((uint)(m * 64 + kg * 16)));
#pragma unroll
        for (int sib = 0; sib < 2; sib++) {
            const int nl = 2 * at + sib;
            const int fi = t4 * 2 + sib;
            f32x4 acc = {b8[fi], b8[fi], b8[fi], b8[fi]};
            acc = __builtin_amdgcn_mfma_f32_16x16x32_bf16(af, *(const s16x8*)&f8[fi], acc, 0, 0, 0);
            if (kg < 2) {
                float v[4] = {fmaxf(acc.x, 0.f), fmaxf(acc.y, 0.f),
                              fmaxf(acc.z, 0.f), fmaxf(acc.w, 0.f)};
#pragma unroll
                for (int j = 0; j < 4; j++) {
                    uint o = (uint)(nl * 512 + (kg * 4 + j) * 64 + m * 2);
                    *(ushort*)(smb + 16384 + fsw(o)) = bfr(v[j]);
                }
            }
        }
    }
    __syncthreads();

    for (int q = 0; q < 8; q++) {
        int n8l = wave * 8 + q;
        int gn8 = n3 * 32 + n8l;
        s16x8 af = *(const s16x8*)(smb + 16384 +
                     fsw((uint)(n8l * 512 + m * 64 + kg * 16)));
        const float* fb = fea_dense + (size_t)gn8 * 1024;
#pragma unroll
        for (int ut = 0; ut < 4; ut++) {
            s16x8 bf = {0, 0, 0, 0, 0, 0, 0, 0};
            if (kg < 2) {
                const float* fp = fb + kg * 512 + ut * 16 + m;
                bf[0] = (short)bfr(fp[0]);   bf[1] = (short)bfr(fp[64]);
                bf[2] = (short)bfr(fp[128]); bf[3] = (short)bfr(fp[192]);
                bf[4] = (short)bfr(fp[256]); bf[5] = (short)bfr(fp[320]);
                bf[6] = (short)bfr(fp[384]); bf[7] = (short)bfr(fp[448]);
            }
            f32x4 acc = {0.f, 0.f, 0.f, 0.f};
            acc = __builtin_amdgcn_mfma_f32_16x16x32_bf16(af, bf, acc, 0, 0, 0);
            float s0 = __shfl_xor(acc.y, 1);
            float s2 = __shfl_xor(acc.w, 1);
            if (kg < 2) {
                int g = gn8 * 32 + ut * 8 + (m >> 1);
                bool odd = (m & 1);
                float v0 = odd ? acc.x : (acc.x - s0) * (1.f / 16384.f);
                float v1 = odd ? acc.z : (acc.z - s2) * (1.f / 16384.f);
                size_t off = (odd ? (size_t)OUT_HALF : (size_t)0) + (size_t)g;
                int b0 = chunk * 4 + kg * 2;
                out[(size_t)b0 * 8192 + off]       = v0;
                out[(size_t)(b0 + 1) * 8192 + off] = v1;
            }
        }
    }
#undef LDFRAG
}

extern "C" void kernel_launch(void* const* d_in, const int* in_sizes, int n_in,
                              void* d_out, int out_size, void* d_ws, size_t ws_size,
                              hipStream_t stream) {
    const float* in_data   = (const float*)d_in[0];
    const float* mid_dense = (const float*)d_in[1];
    const float* in_filter = (const float*)d_in[2];
    const float* in_bias   = (const float*)d_in[3];
    const float* filters   = (const float*)d_in[4];
    const float* biases    = (const float*)d_in[5];
    const float* fea_dense = (const float*)d_in[6];
    float* out = (float*)d_out;
    uint* S3   = (uint*)d_ws;   // 4 MB

    // MEASUREMENT: A x4 (idempotent) to split T_A vs T_BC from dur_us.
    for (int r = 0; r < 4; r++)
        ibf_A<<<dim3(256, 4), 256, 0, stream>>>(in_data, mid_dense, in_filter, in_bias,
                                                filters, biases, S3);
    ibf_BC<<<dim3(8, 64), 256, 0, stream>>>(filters, biases, fea_dense, S3, out);
}

// Round 15
// 37.978 us; speedup vs baseline: 2.1907x; 2.1907x over previous
//
#include <hip/hip_runtime.h>
#include <hip/hip_bf16.h>

// InvButterflyLayer via MFMA (bf16 in, fp32 accum). B=256, MID=16384, C=16.
// Live cone: level lvl needs t < 2^(8-lvl); lvl0 t<256 -> x[0:8224).
//
// R15 vs R13: (1) BC dense tail software-pipelined (FE loads for q+1 issued
// during q's compute); (2) BC S3-stage loads issued first; (3) A weight
// staging via float4 (4x fewer loads); (4) extern __shared__ used directly
// (no char* params -> guaranteed LDS addrspace lowering).

#define OUT_HALF 2097152

typedef __attribute__((ext_vector_type(4))) float f32x4;
typedef __attribute__((ext_vector_type(8))) short s16x8;

extern __shared__ char smb[];

__device__ __forceinline__ uint fsw(uint a) {
    return a ^ ((((a >> 6) ^ (a >> 8)) & 3u) << 4);
}
__device__ __forceinline__ ushort bfr(float f) {
    __hip_bfloat16 h = __float2bfloat16(f);
    union { __hip_bfloat16 h; ushort u; } cv; cv.h = h; return cv.u;
}
__device__ __forceinline__ uint pk(float a, float b) {
    return (uint)bfr(a) | ((uint)bfr(b) << 16);
}

// Generic tree level (kernel A): A[plane p][16-row tiles] x W[child] -> next A.
__device__ __forceinline__ void tree_level(
    const int lane, const int wave,
    uint AOff, uint NOff, int lgR, int lgNP, int nTiles,
    uint WOff, int wnb, uint LBOff, int bnb)
{
    const int m  = lane & 15;
    const int kg = lane >> 4;
    const int lgTPP = lgR - 4;
    for (int at = wave; at < nTiles; at += 4) {
        const int p  = at >> lgTPP;
        const int tc = at & ((1 << lgTPP) - 1);
        const int np = p & ((1 << lgNP) - 1);
        const int ii = p >> lgNP;
        s16x8 af = *(const s16x8*)(smb + AOff + (p << (lgR + 6)) +
                                   fsw((uint)((tc * 16 + m) * 64 + kg * 16)));
#pragma unroll
        for (int sib = 0; sib < 2; sib++) {
            const int nl = 2 * np + sib;
            s16x8 bf = *(const s16x8*)(smb + WOff +
                         fsw((uint)((wnb + nl) * 1024 + m * 64 + kg * 16)));
            float bv = *(const float*)(smb + LBOff + ((bnb + nl) * 16 + m) * 4);
            f32x4 acc = {bv, bv, bv, bv};
            acc = __builtin_amdgcn_mfma_f32_16x16x32_bf16(af, bf, acc, 0, 0, 0);
            const int p2 = (ii << (lgNP + 1)) + nl;
            const uint wb = NOff + (p2 << (lgR + 5));
            const int r2 = tc * 8 + kg * 2;
            *(uint*)(smb + wb + fsw((uint)(r2 * 64 + m * 4))) =
                pk(fmaxf(acc.x, 0.f), fmaxf(acc.y, 0.f));
            *(uint*)(smb + wb + fsw((uint)((r2 + 1) * 64 + m * 4))) =
                pk(fmaxf(acc.z, 0.f), fmaxf(acc.w, 0.f));
        }
    }
}

// ===================== Kernel A =====================
// LDS map (bytes): X@0[8256] (-> A2@0) | A1/A3@8320[4096] | W@12416[14336]
//                  BT0@26752[2048] LB@28800[960]  total 29760
__global__ __launch_bounds__(256, 4)
void ibf_A(const float* __restrict__ in_data, const float* __restrict__ mid_dense,
           const float* __restrict__ in_filter, const float* __restrict__ in_bias,
           const float* __restrict__ filters, const float* __restrict__ biases,
           uint* __restrict__ S3)
{
    const int tid = threadIdx.x, lane = tid & 63, wave = tid >> 6;
    const int b = blockIdx.x;
    const int th = blockIdx.y >> 1;
    const int i  = blockIdx.y & 1;

    {
        const float4* inb = (const float4*)in_data + (size_t)b * 8192 + th * 2048;
        const float4* mdb = (const float4*)mid_dense + th * 2048;
        for (int mp = tid; mp < 2064; mp += 256) {
            float4 iv = inb[mp], mv = mdb[mp];
            float xa = i ? iv.y * mv.y : iv.x * mv.x;
            float xb = i ? iv.w * mv.w : iv.z * mv.z;
            *(uint*)(smb + fsw((uint)(mp * 4))) = pk(xa, xb);
        }
    }
    // lvl1-3 weights via float4: W[nidx][d][k2=2c+par] <- pk(W[k=0][c][d], W[k=1][c][d])
    for (int t = tid; t < 896; t += 256) {
        int nidx = t >> 6, r = t & 63, c = r >> 2, d4 = (r & 3) * 4;
        int lvl = (nidx < 2) ? 1 : ((nidx < 6) ? 2 : 3);
        int n = nidx - ((1 << lvl) - 2);
        const float* src = filters + (size_t)(lvl - 1) * 131072 + n * 512 + c * 16 + d4;
        float4 v0 = *(const float4*)(src);
        float4 v1 = *(const float4*)(src + 256);
        const float* p0 = &v0.x;
        const float* p1 = &v1.x;
#pragma unroll
        for (int j = 0; j < 4; j++) {
            *(uint*)(smb + 12416 + fsw((uint)(nidx * 1024 + (d4 + j) * 64 + c * 4))) =
                pk(p0[j], p1[j]);
        }
    }
    for (int t = tid; t < 512; t += 256) {
        int c = t >> 5, w2 = t & 31;
        *(uint*)(smb + 26752 + fsw((uint)(c * 128 + w2 * 4))) =
            pk(in_filter[(2 * w2) * 16 + c], in_filter[(2 * w2 + 1) * 16 + c]);
    }
    if (tid < 240) {
        float v;
        if (tid < 224) {
            int nidx = tid >> 4;
            int lvl = (nidx < 2) ? 1 : ((nidx < 6) ? 2 : 3);
            int n = nidx - ((1 << lvl) - 2);
            v = biases[(size_t)(lvl - 1) * 4096 + n * 16 + (tid & 15)];
        } else v = in_bias[tid - 224];
        *(float*)(smb + 28800 + tid * 4) = v;
    }
    __syncthreads();

    {
        const int m = lane & 15, kg = lane >> 4;
        s16x8 b0 = *(const s16x8*)(smb + 26752 + fsw((uint)(m * 128 + kg * 16)));
        s16x8 b1 = *(const s16x8*)(smb + 26752 + fsw((uint)(m * 128 + 64 + kg * 16)));
        float bv = *(const float*)(smb + 28800 + (224 + m) * 4);
        for (int at = wave; at < 8; at += 4) {
            int tc = at;
            s16x8 a0 = *(const s16x8*)(smb + fsw((uint)((tc * 16 + m) * 64 + kg * 16)));
            s16x8 a1 = *(const s16x8*)(smb + fsw((uint)((tc * 16 + m) * 64 + 64 + kg * 16)));
            f32x4 acc = {bv, bv, bv, bv};
            acc = __builtin_amdgcn_mfma_f32_16x16x32_bf16(a0, b0, acc, 0, 0, 0);
            acc = __builtin_amdgcn_mfma_f32_16x16x32_bf16(a1, b1, acc, 0, 0, 0);
            int r2 = tc * 8 + kg * 2;
            *(uint*)(smb + 8320 + fsw((uint)(r2 * 64 + m * 4))) =
                pk(fmaxf(acc.x, 0.f), fmaxf(acc.y, 0.f));
            *(uint*)(smb + 8320 + fsw((uint)((r2 + 1) * 64 + m * 4))) =
                pk(fmaxf(acc.z, 0.f), fmaxf(acc.w, 0.f));
        }
    }
    __syncthreads();
    tree_level(lane, wave, 8320, 0,    6, 0, 4, 12416, 0, 28800, 0);  // lvl1
    __syncthreads();
    tree_level(lane, wave, 0,    8320, 5, 1, 4, 12416, 2, 28800, 2);  // lvl2
    __syncthreads();
    {
        const int m = lane & 15, kg = lane >> 4;
        for (int at = wave; at < 4; at += 4) {
            s16x8 af = *(const s16x8*)(smb + 8320 + (at << 10) + fsw((uint)(m * 64 + kg * 16)));
#pragma unroll
            for (int sib = 0; sib < 2; sib++) {
                int n3 = 2 * at + sib;
                s16x8 bf = *(const s16x8*)(smb + 12416 +
                             fsw((uint)((6 + n3) * 1024 + m * 64 + kg * 16)));
                float bv = *(const float*)(smb + 28800 + ((6 + n3) * 16 + m) * 4);
                f32x4 acc = {bv, bv, bv, bv};
                acc = __builtin_amdgcn_mfma_f32_16x16x32_bf16(af, bf, acc, 0, 0, 0);
                int bi = 2 * b + i;
                int t4 = th * 8 + kg * 2;
                uint idx = ((uint)(n3 * 512 + bi) * 16 + t4) * 16 + m;
                S3[idx]      = pk(fmaxf(acc.x, 0.f), fmaxf(acc.y, 0.f));
                S3[idx + 16] = pk(fmaxf(acc.z, 0.f), fmaxf(acc.w, 0.f));
            }
        }
    }
}

// ========== Kernel BC: lvl4-8 (register weights) + dense + recombine ==========
// LDS: P0@0[8192] P1@8192[8192] AF@16384[16384 + fsw slack] total 33536
__global__ __launch_bounds__(256, 2)
void ibf_BC(const float* __restrict__ filters, const float* __restrict__ biases,
            const float* __restrict__ fea_dense, const uint* __restrict__ S3,
            float* __restrict__ out)
{
    const int tid = threadIdx.x, lane = tid & 63, wave = tid >> 6;
    const int n3 = blockIdx.x, chunk = blockIdx.y;
    const int m = lane & 15, kg = lane >> 4;

    // ---- S3 stage FIRST (earliest global-load issue) ----
    {
        const char* src = (const char*)S3 + ((size_t)n3 * 512 + chunk * 8) * 1024;
        for (int ci = tid; ci < 512; ci += 256)
            *(float4*)(smb + fsw((uint)(ci * 16))) = *(const float4*)(src + ci * 16);
    }
    // zero AF region (padded K cols / rows must be 0, not stale: R12 lesson)
    for (int o = tid * 16; o < 16384; o += 4096)
        *(float4*)(smb + 16384 + o) = make_float4(0.f, 0.f, 0.f, 0.f);

    const float* FB1 = filters + (size_t)3 * 131072 + ((size_t)(n3 << 1)) * 512;
    const float* FB2 = filters + (size_t)4 * 131072 + ((size_t)(n3 << 2)) * 512;
    const float* FB3 = filters + (size_t)5 * 131072 + ((size_t)(n3 << 3)) * 512;
    const float* FB4 = filters + (size_t)6 * 131072 + ((size_t)(n3 << 4)) * 512;
    const float* FB5 = filters + (size_t)7 * 131072 + ((size_t)(n3 << 5)) * 512;
    const float* BB1 = biases + (size_t)3 * 4096 + (n3 << 1) * 16;
    const float* BB2 = biases + (size_t)4 * 4096 + (n3 << 2) * 16;
    const float* BB3 = biases + (size_t)5 * 4096 + (n3 << 3) * 16;
    const float* BB4 = biases + (size_t)6 * 4096 + (n3 << 4) * 16;
    const float* BB5 = biases + (size_t)7 * 4096 + (n3 << 5) * 16;

#define LDFRAG(dst, fb, nl)                                                  \
    {                                                                        \
        const float* s_ = (fb) + (nl) * 512 + m;                             \
        _Pragma("unroll")                                                    \
        for (int c4 = 0; c4 < 4; c4++) {                                     \
            int c_ = kg * 4 + c4;                                            \
            (&(dst).x)[c4] = pk(s_[c_ * 16], s_[256 + c_ * 16]);             \
        }                                                                    \
    }

    uint4 f4[2], f5[4];
    float b4[2], b5[4];
    LDFRAG(f4[0], FB1, 0); LDFRAG(f4[1], FB1, 1);
    b4[0] = BB1[m]; b4[1] = BB1[16 + m];
#pragma unroll
    for (int s = 0; s < 4; s++) { LDFRAG(f5[s], FB2, s); b5[s] = BB2[s * 16 + m]; }
    __syncthreads();

    // ---- lvl4 (P0 -> P1); issue lvl6 frags ----
    uint4 f6[4];
    float b6[4];
    {
        const int n0 = (wave >> 1) * 2;
        LDFRAG(f6[0], FB3, n0);     b6[0] = BB3[(n0) * 16 + m];
        LDFRAG(f6[1], FB3, n0 + 1); b6[1] = BB3[(n0 + 1) * 16 + m];
        LDFRAG(f6[2], FB3, n0 + 4); b6[2] = BB3[(n0 + 4) * 16 + m];
        LDFRAG(f6[3], FB3, n0 + 5); b6[3] = BB3[(n0 + 5) * 16 + m];
    }
#pragma unroll
    for (int t2 = 0; t2 < 2; t2++) {
        const int tc = wave + t2 * 4;
        s16x8 af = *(const s16x8*)(smb + fsw((uint)((tc * 16 + m) * 64 + kg * 16)));
#pragma unroll
        for (int sib = 0; sib < 2; sib++) {
            f32x4 acc = {b4[sib], b4[sib], b4[sib], b4[sib]};
            acc = __builtin_amdgcn_mfma_f32_16x16x32_bf16(af, *(const s16x8*)&f4[sib], acc, 0, 0, 0);
            const uint wb = 8192u + (uint)sib * 4096u;
            const int r2 = tc * 8 + kg * 2;
            *(uint*)(smb + wb + fsw((uint)(r2 * 64 + m * 4))) = pk(fmaxf(acc.x, 0.f), fmaxf(acc.y, 0.f));
            *(uint*)(smb + wb + fsw((uint)((r2 + 1) * 64 + m * 4))) = pk(fmaxf(acc.z, 0.f), fmaxf(acc.w, 0.f));
        }
    }
    __syncthreads();

    // ---- lvl5 (P1 -> P0); issue lvl7 frags ----
    uint4 f7[4];
    float b7[4];
    {
        LDFRAG(f7[0], FB4, 2 * wave);     b7[0] = BB4[(2 * wave) * 16 + m];
        LDFRAG(f7[1], FB4, 2 * wave + 1); b7[1] = BB4[(2 * wave + 1) * 16 + m];
        LDFRAG(f7[2], FB4, 2 * wave + 8); b7[2] = BB4[(2 * wave + 8) * 16 + m];
        LDFRAG(f7[3], FB4, 2 * wave + 9); b7[3] = BB4[(2 * wave + 9) * 16 + m];
    }
#pragma unroll
    for (int t2 = 0; t2 < 2; t2++) {
        const int at = wave + t2 * 4;
        const int p = at >> 2, tc = at & 3;
        s16x8 af = *(const s16x8*)(smb + 8192 + p * 4096 + fsw((uint)((tc * 16 + m) * 64 + kg * 16)));
#pragma unroll
        for (int sib = 0; sib < 2; sib++) {
            const int nl = 2 * p + sib;
            f32x4 acc = {b5[nl], b5[nl], b5[nl], b5[nl]};
            acc = __builtin_amdgcn_mfma_f32_16x16x32_bf16(af, *(const s16x8*)&f5[nl], acc, 0, 0, 0);
            const uint wb = (uint)nl * 2048u;
            const int r2 = tc * 8 + kg * 2;
            *(uint*)(smb + wb + fsw((uint)(r2 * 64 + m * 4))) = pk(fmaxf(acc.x, 0.f), fmaxf(acc.y, 0.f));
            *(uint*)(smb + wb + fsw((uint)((r2 + 1) * 64 + m * 4))) = pk(fmaxf(acc.z, 0.f), fmaxf(acc.w, 0.f));
        }
    }
    __syncthreads();

    // ---- lvl6 (P0 -> P1); issue lvl8 frags ----
    uint4 f8[8];
    float b8[8];
#pragma unroll
    for (int t4 = 0; t4 < 4; t4++) {
        const int at = wave + 4 * t4;
        LDFRAG(f8[2 * t4],     FB5, 2 * at);     b8[2 * t4]     = BB5[(2 * at) * 16 + m];
        LDFRAG(f8[2 * t4 + 1], FB5, 2 * at + 1); b8[2 * t4 + 1] = BB5[(2 * at + 1) * 16 + m];
    }
#pragma unroll
    for (int t2 = 0; t2 < 2; t2++) {
        const int at = wave + t2 * 4;
        const int p = at >> 1, tc = at & 1;
        s16x8 af = *(const s16x8*)(smb + p * 2048 + fsw((uint)((tc * 16 + m) * 64 + kg * 16)));
#pragma unroll
        for (int sib = 0; sib < 2; sib++) {
            const int nl = 2 * p + sib;
            const int fi = t2 * 2 + sib;
            f32x4 acc = {b6[fi], b6[fi], b6[fi], b6[fi]};
            acc = __builtin_amdgcn_mfma_f32_16x16x32_bf16(af, *(const s16x8*)&f6[fi], acc, 0, 0, 0);
            const uint wb = 8192u + (uint)nl * 1024u;
            const int r2 = tc * 8 + kg * 2;
            *(uint*)(smb + wb + fsw((uint)(r2 * 64 + m * 4))) = pk(fmaxf(acc.x, 0.f), fmaxf(acc.y, 0.f));
            *(uint*)(smb + wb + fsw((uint)((r2 + 1) * 64 + m * 4))) = pk(fmaxf(acc.z, 0.f), fmaxf(acc.w, 0.f));
        }
    }
    __syncthreads();

    // ---- lvl7 (P1 -> P0) ----
#pragma unroll
    for (int t2 = 0; t2 < 2; t2++) {
        const int p = wave + t2 * 4;
        s16x8 af = *(const s16x8*)(smb + 8192 + p * 1024 + fsw((uint)(m * 64 + kg * 16)));
#pragma unroll
        for (int sib = 0; sib < 2; sib++) {
            const int nl = 2 * p + sib;
            const int fi = t2 * 2 + sib;
            f32x4 acc = {b7[fi], b7[fi], b7[fi], b7[fi]};
            acc = __builtin_amdgcn_mfma_f32_16x16x32_bf16(af, *(const s16x8*)&f7[fi], acc, 0, 0, 0);
            const uint wb = (uint)nl * 512u;
            const int r2 = kg * 2;
            *(uint*)(smb + wb + fsw((uint)(r2 * 64 + m * 4))) = pk(fmaxf(acc.x, 0.f), fmaxf(acc.y, 0.f));
            *(uint*)(smb + wb + fsw((uint)((r2 + 1) * 64 + m * 4))) = pk(fmaxf(acc.z, 0.f), fmaxf(acc.w, 0.f));
        }
    }
    __syncthreads();

    // ---- lvl8 (P0 planes at*512 -> AF, full-offset fsw layout) ----
#pragma unroll
    for (int t4 = 0; t4 < 4; t4++) {
        const int at = wave + 4 * t4;
        s16x8 af = *(const s16x8*)(smb + at * 512 + fsw((uint)(m * 64 + kg * 16)));
#pragma unroll
        for (int sib = 0; sib < 2; sib++) {
            const int nl = 2 * at + sib;
            const int fi = t4 * 2 + sib;
            f32x4 acc = {b8[fi], b8[fi], b8[fi], b8[fi]};
            acc = __builtin_amdgcn_mfma_f32_16x16x32_bf16(af, *(const s16x8*)&f8[fi], acc, 0, 0, 0);
            if (kg < 2) {
                float v[4] = {fmaxf(acc.x, 0.f), fmaxf(acc.y, 0.f),
                              fmaxf(acc.z, 0.f), fmaxf(acc.w, 0.f)};
#pragma unroll
                for (int j = 0; j < 4; j++) {
                    uint o = (uint)(nl * 512 + (kg * 4 + j) * 64 + m * 2);
                    *(ushort*)(smb + 16384 + fsw(o)) = bfr(v[j]);
                }
            }
        }
    }
    __syncthreads();

    // ---- dense 16->64 + recombine, 2-deep FE software pipeline ----
    {
        float feA[32], feB[32];
        const float* fbase = fea_dense + (size_t)(n3 * 32 + wave * 8) * 1024 + kg * 512 + m;
        if (kg < 2) {
#pragma unroll
            for (int ut = 0; ut < 4; ut++)
#pragma unroll
                for (int j = 0; j < 8; j++)
                    feA[ut * 8 + j] = fbase[ut * 16 + j * 64];   // q = 0
        }
#pragma unroll
        for (int q = 0; q < 8; q++) {
            float* cur = (q & 1) ? feB : feA;
            float* nxt = (q & 1) ? feA : feB;
            if (q < 7 && kg < 2) {
                const float* fn = fbase + (size_t)(q + 1) * 1024;
#pragma unroll
                for (int ut = 0; ut < 4; ut++)
#pragma unroll
                    for (int j = 0; j < 8; j++)
                        nxt[ut * 8 + j] = fn[ut * 16 + j * 64];
            }
            const int n8l = wave * 8 + q;
            const int gn8 = n3 * 32 + n8l;
            s16x8 af = *(const s16x8*)(smb + 16384 +
                         fsw((uint)(n8l * 512 + m * 64 + kg * 16)));
#pragma unroll
            for (int ut = 0; ut < 4; ut++) {
                s16x8 bf = {0, 0, 0, 0, 0, 0, 0, 0};
                if (kg < 2) {
#pragma unroll
                    for (int j = 0; j < 8; j++)
                        bf[j] = (short)bfr(cur[ut * 8 + j]);
                }
                f32x4 acc = {0.f, 0.f, 0.f, 0.f};
                acc = __builtin_amdgcn_mfma_f32_16x16x32_bf16(af, bf, acc, 0, 0, 0);
                float s0 = __shfl_xor(acc.y, 1);
                float s2 = __shfl_xor(acc.w, 1);
                if (kg < 2) {
                    int g = gn8 * 32 + ut * 8 + (m >> 1);
                    bool odd = (m & 1);
                    float v0 = odd ? acc.x : (acc.x - s0) * (1.f / 16384.f);
                    float v1 = odd ? acc.z : (acc.z - s2) * (1.f / 16384.f);
                    size_t off = (odd ? (size_t)OUT_HALF : (size_t)0) + (size_t)g;
                    int b0 = chunk * 4 + kg * 2;
                    out[(size_t)b0 * 8192 + off]       = v0;
                    out[(size_t)(b0 + 1) * 8192 + off] = v1;
                }
            }
        }
    }
#undef LDFRAG
}

extern "C" void kernel_launch(void* const* d_in, const int* in_sizes, int n_in,
                              void* d_out, int out_size, void* d_ws, size_t ws_size,
                              hipStream_t stream) {
    const float* in_data   = (const float*)d_in[0];
    const float* mid_dense = (const float*)d_in[1];
    const float* in_filter = (const float*)d_in[2];
    const float* in_bias   = (const float*)d_in[3];
    const float* filters   = (const float*)d_in[4];
    const float* biases    = (const float*)d_in[5];
    const float* fea_dense = (const float*)d_in[6];
    float* out = (float*)d_out;
    uint* S3   = (uint*)d_ws;   // 4 MB

    ibf_A<<<dim3(256, 4), 256, 29760, stream>>>(in_data, mid_dense, in_filter, in_bias,
                                                filters, biases, S3);
    ibf_BC<<<dim3(8, 64), 256, 33536, stream>>>(filters, biases, fea_dense, S3, out);
}